// Round 7
// baseline (1632.548 us; speedup 1.0000x reference)
//
#include <hip/hip_runtime.h>
#include <math.h>

// KoLeo loss: dist_i = sqrt(2 - 2*max_{j!=i} <fhat_i, fhat_j>); loss = -mean(log(dist+1e-8))
// R16: LDS-free register-direct Gram via granule-transposed global layout.
// Evidence (R9-R15): six schedules, all 186-213 us at 28-32% MfmaUtil; LDS
// bank-conflict cost constant at 4 cy per ds_read_b128 across ALL rounds
// (pattern-intrinsic); per-CU LDS-pipe time (~83+14 us) co-critical with MFMA
// (59 us) and barrier-coupled in every LDS-staged structure. R11 showed
// register-direct fails ONLY from strided frag loads (16-line splits).
// Fix: normalize_t packs fp8 as F8T[row/16][granule][row%16][16B] so a
// fragment load = 64 lanes x 16B = eight fully-consumed 128B lines.
// gemm: NO LDS, NO barriers in main loop; 8 free-running waves (2x4 grid,
// 128x64 per wave); A-frags prefetched 2 groups ahead in a 4-deep static
// rotation (slot = mi&3); B-frags tile-double-buffered (breg[kt&1], static
// under full unroll, rule #20); sched_barrier(0) pins group issue order;
// compiler inserts exact counted vmcnt for C-level loads (never drains to 0
// mid-loop since prefetch distance = 2 groups). Regs: acc 128 + A 32 + B 64
// + addr ~15 -> 2 waves/SIMD. L2 demand 64-192 KB/block-tile vs ~60 B/cy/CU;
// L1 absorbs wave-redundancy (waves share A slabs 4x, B 2x).
// Features pre-scaled x16 before e4m3 cast; raw dots carry x256, folded out in
// row_reduce (max is monotone). Each tile yields row-max AND col-max.

#define N_ROWS 16384
#define DIM 1024
#define BT 256
#define NKT 8                     // K-tiles of 128 fp8 elements
#define NT (N_ROWS / BT)          // 64
#define NBLK (NT * (NT + 1) / 2)  // 2080 (divisible by 8 -> XCD swizzle)

typedef int   i32x4 __attribute__((ext_vector_type(4)));
typedef int   i32x8 __attribute__((ext_vector_type(8)));
typedef float f32x4 __attribute__((ext_vector_type(4)));

#define SB0 __builtin_amdgcn_sched_barrier(0)

// ------------------------------------------- normalize + granule-transpose
// F8T layout: tile tt (16 rows), granule g (16B), row r: byte offset
// tt*16384 + g*256 + r*16. Same fp8 bytes as linear layout, rearranged.
__global__ __launch_bounds__(256) void normalize_t(
    const float* __restrict__ in, unsigned char* __restrict__ f8t) {
  const int t = threadIdx.x;
  const int r = t >> 4, c = t & 15;  // 16 rows x 16 chunks
  const float4* rowp =
      (const float4*)(in + (size_t)(blockIdx.x * 16 + r) * DIM);
  float4 v[16];
  float ss = 0.f;
#pragma unroll
  for (int i = 0; i < 16; ++i) {
    v[i] = rowp[c + 16 * i];
    ss += v[i].x * v[i].x + v[i].y * v[i].y + v[i].z * v[i].z + v[i].w * v[i].w;
  }
#pragma unroll
  for (int s = 1; s < 16; s <<= 1) ss += __shfl_xor(ss, s, 64);  // within-row
  const float scale = 16.f / fmaxf(sqrtf(ss), 1e-12f);

  __shared__ unsigned int lt[16 * 256];  // [row][u32-quad], xor-swizzled
#pragma unroll
  for (int i = 0; i < 16; ++i) {
    unsigned int w =
        __builtin_amdgcn_cvt_pk_fp8_f32(v[i].x * scale, v[i].y * scale, 0, false);
    w = __builtin_amdgcn_cvt_pk_fp8_f32(v[i].z * scale, v[i].w * scale, w, true);
    lt[r * 256 + ((c + 16 * i) ^ ((r & 7) << 2))] = w;
  }
  __syncthreads();
  int4* outp = (int4*)(f8t + (size_t)blockIdx.x * 16384);
  const int4* ltv = (const int4*)lt;
#pragma unroll
  for (int p = 0; p < 4; ++p) {
    const int o = p * 256 + t;        // output granule-slot
    const int g = o >> 4, rr = o & 15;
    outp[o] = ltv[rr * 64 + (g ^ (rr & 7))];  // 16B at word (4g)^((rr&7)<<2)
  }
}

// Load one 32B fragment: granules 2q,2q+1 of a 16-row tile (coalesced:
// lanes cover 4x512B windows, lo/hi at +0/+256 within each).
#define LOADG(dst, base, off)                                        \
  do {                                                               \
    i32x4 _lo = *(const i32x4*)((base) + (off) + lane_off);          \
    i32x4 _hi = *(const i32x4*)((base) + (off) + lane_off + 256);    \
    dst = __builtin_shufflevector(_lo, _hi, 0, 1, 2, 3, 4, 5, 6, 7); \
  } while (0)

// -------------------------------------------------- Gram row/col-max GEMM
__global__ __launch_bounds__(512, 2) void gemm_rowmax(
    const unsigned char* __restrict__ F, float* __restrict__ partial) {
  // XCD-chunked bijective swizzle (2080 % 8 == 0), then triangular decode
  int bid = blockIdx.x;
  bid = (bid & 7) * (NBLK / 8) + (bid >> 3);
  double disc = (double)(2 * NT + 1) * (2 * NT + 1) - 8.0 * (double)bid;
  int it = (int)(((2 * NT + 1) - sqrt(disc)) * 0.5);
  if (it > NT - 1) it = NT - 1;
  while (it > 0 && it * NT - it * (it - 1) / 2 > bid) --it;
  while ((it + 1) * NT - (it + 1) * it / 2 <= bid) ++it;
  const int jt = it + (bid - (it * NT - it * (it - 1) / 2));

  const int ibase = it * BT, jbase = jt * BT;
  const int tid = threadIdx.x;
  const int wave = tid >> 6, lane = tid & 63;
  const int wi = wave >> 2, wj = wave & 3;  // 2x4 wave grid, 128x64 each
  const int quad = lane >> 4, r16 = lane & 15;

  // wave-local panel bases (granule-transposed layout)
  const unsigned char* FAw = F + (size_t)ibase * 1024 + (size_t)wi * 131072;
  const unsigned char* FBw = F + (size_t)jbase * 1024 + (size_t)wj * 65536;
  const unsigned int lane_off = (unsigned int)(quad * 512 + r16 * 16);

  // A-frag (mi, kt) at FAw + mi*16384 + kt*2048; B-frag (ni, kt) likewise.
  f32x4 acc[8][4] = {};       // [mi][ni] 16x16 tiles (AGPR-resident)
  i32x8 areg[4], breg[2][4];  // A: 4-deep rotation; B: tile ping-pong

  // prologue: A(0,0),A(1,0) + B(*,0)
  LOADG(areg[0], FAw, 0);
  LOADG(areg[1], FAw, 16384);
  LOADG(breg[0][0], FBw, 0);
  LOADG(breg[0][1], FBw, 16384);
  LOADG(breg[0][2], FBw, 32768);
  LOADG(breg[0][3], FBw, 49152);

  // main loop: fully unrolled, all register indices compile-time (rule #20).
  // Group (kt,mi): prefetch A-frag flat n=kt*8+mi+2 (2 groups ahead) into
  // slot (mi+2)&3; groups mi>=4 also prefetch one B-frag of tile kt+1.
  // Compiler-counted vmcnt covers each load with >=2 groups (~550 cy) of MFMA.
#pragma unroll
  for (int kt = 0; kt < NKT; ++kt) {
#pragma unroll
    for (int mi = 0; mi < 8; ++mi) {
      const int n = kt * 8 + mi + 2;  // A prefetch target (flat)
      if (n < 64)
        LOADG(areg[(mi + 2) & 3], FAw, (n & 7) * 16384 + (n >> 3) * 2048);
      if (kt < NKT - 1 && mi >= 4)
        LOADG(breg[(kt & 1) ^ 1][mi - 4], FBw,
              (mi - 4) * 16384 + (kt + 1) * 2048);
      SB0;
      __builtin_amdgcn_s_setprio(1);
#pragma unroll
      for (int ni = 0; ni < 4; ++ni)
        acc[mi][ni] = __builtin_amdgcn_mfma_scale_f32_16x16x128_f8f6f4(
            areg[mi & 3], breg[kt & 1][ni], acc[mi][ni], 0, 0,  // fp8/fp8
            0, 0x7F7F7F7F, 0, 0x7F7F7F7F);                      // unit scales
      __builtin_amdgcn_s_setprio(0);
      SB0;
    }
  }

  // ---------------- epilogue: row/col max (small dedicated LDS)
  __shared__ float red[BT][4];   // row-max partials over wj
  __shared__ float redc[BT][2];  // col-max partials over wi

  // C/D layout (16x16): col = lane&15, row = quad*4 + reg.
#pragma unroll
  for (int mi = 0; mi < 8; ++mi) {
#pragma unroll
    for (int r = 0; r < 4; ++r) {
      const int rl = wi * 128 + mi * 16 + quad * 4 + r;
      const int rowg = ibase + rl;
      float m = -INFINITY;
#pragma unroll
      for (int ni = 0; ni < 4; ++ni) {
        const int colg = jbase + wj * 64 + ni * 16 + r16;
        const float v = acc[mi][ni][r];
        m = (rowg == colg) ? m : fmaxf(m, v);
      }
#pragma unroll
      for (int s = 1; s < 16; s <<= 1) m = fmaxf(m, __shfl_xor(m, s, 64));
      if (r16 == 0) red[rl][wj] = m;
    }
  }
  if (it != jt) {  // col-max (off-diagonal tiles: no diag elements present)
#pragma unroll
    for (int ni = 0; ni < 4; ++ni) {
      float m = -INFINITY;
#pragma unroll
      for (int mi = 0; mi < 8; ++mi)
#pragma unroll
        for (int r = 0; r < 4; ++r) m = fmaxf(m, acc[mi][ni][r]);
      m = fmaxf(m, __shfl_xor(m, 16, 64));  // reduce across quads
      m = fmaxf(m, __shfl_xor(m, 32, 64));
      if (quad == 0) redc[wj * 64 + ni * 16 + r16][wi] = m;
    }
  }
  __syncthreads();
  if (tid < BT) {
    const float a = fmaxf(red[tid][0], red[tid][1]);
    const float b = fmaxf(red[tid][2], red[tid][3]);
    partial[(size_t)jt * N_ROWS + ibase + tid] = fmaxf(a, b);
  } else if (it != jt) {
    const int c = tid - BT;
    partial[(size_t)it * N_ROWS + jbase + c] = fmaxf(redc[c][0], redc[c][1]);
  }
}

// ------------------------------------------------------------- reductions
__global__ __launch_bounds__(256) void row_reduce(
    const float* __restrict__ partial, float* __restrict__ blocksum) {
  const int r = blockIdx.x * 256 + threadIdx.x;
  float m = -INFINITY;
  for (int p = 0; p < NT; ++p)
    m = fmaxf(m, partial[(size_t)p * N_ROWS + r]);
  // raw dot carries x256 (features scaled x16): 2 - 2*(m/256) = 2 - m/128
  const float d2 = fmaxf(2.f - m * (1.f / 128.f), 0.f);
  float term = logf(sqrtf(d2) + 1e-8f);
#pragma unroll
  for (int s = 1; s < 64; s <<= 1) term += __shfl_xor(term, s, 64);
  __shared__ float wsum[4];
  const int wave = threadIdx.x >> 6, lane = threadIdx.x & 63;
  if (lane == 0) wsum[wave] = term;
  __syncthreads();
  if (threadIdx.x == 0)
    blocksum[blockIdx.x] = wsum[0] + wsum[1] + wsum[2] + wsum[3];
}

__global__ void finalize(const float* __restrict__ blocksum,
                         float* __restrict__ out) {
  float v = blocksum[threadIdx.x];
#pragma unroll
  for (int s = 1; s < 64; s <<= 1) v += __shfl_xor(v, s, 64);
  if (threadIdx.x == 0) out[0] = -v / (float)N_ROWS;
}

// ---------------------------------------------------------------- launcher
extern "C" void kernel_launch(void* const* d_in, const int* in_sizes, int n_in,
                              void* d_out, int out_size, void* d_ws, size_t ws_size,
                              hipStream_t stream) {
  const float* feats = (const float*)d_in[0];
  float* out = (float*)d_out;
  char* ws = (char*)d_ws;

  // ws: [0,16MB) granule-transposed fp8; [16MB,20MB) partial [64][16384] f32.
  unsigned char* f8t = (unsigned char*)ws;
  float* partial = (float*)(ws + (size_t)N_ROWS * DIM);
  float* blocksum =
      (float*)(ws + (size_t)N_ROWS * DIM + (size_t)NT * N_ROWS * 4);

  normalize_t<<<N_ROWS / 16, 256, 0, stream>>>(feats, f8t);
  gemm_rowmax<<<NBLK, 512, 0, stream>>>(f8t, partial);
  row_reduce<<<N_ROWS / 256, 256, 0, stream>>>(partial, blocksum);
  finalize<<<1, 64, 0, stream>>>(blocksum, out);
}

// Round 8
// 312.629 us; speedup vs baseline: 5.2220x; 5.2220x over previous
//
#include <hip/hip_runtime.h>
#include <math.h>

// KoLeo loss: dist_i = sqrt(2 - 2*max_{j!=i} <fhat_i, fhat_j>); loss = -mean(log(dist+1e-8))
// R17 = R13 (best verified: 256^2 tile, 16 waves of 64x64, 128 KiB LDS dbuf,
// counted-vmcnt staging ladder, 2 barriers/K-tile) with ONE variable changed:
// MFMA shape 16x16x128 -> 32x32x64 (mfma_scale f8f6f4).
// Rationale: R9-R15 pin every schedule at 28-32% MfmaUtil with ~4300
// unaccounted cy/K-tile/SIMD; learn-loop's own MX-fp8 reference (m148) hits
// the same ~35% wall in a structure where bf16 reaches 62%. Suspect: per-MFMA
// operand traffic (8+8 A/B regs + scales per 34.6 cy) in mixed streams.
// 32x32x64 does 2x FLOP on the same 8+8 A/B regs -> halves per-FLOP operand
// reads and MFMA instruction count. Same LDS bytes, same staging, same FLOP.
// Regs: acc 4x f32x16 = 64 + 4 live frags 32 + addr ~15 -> fits 128 @ 4w/SIMD.
// A/B frag layout (32x32x64): lane l = row l&31, k-bytes (l>>5)*32+[0,32).
// C/D layout (32x32): col = lane&31, row = (reg&3)+8*(reg>>2)+4*(lane>>5).
// 16B-granule XOR swizzle, linear gload_lds dest + pre-swizzled source.
// Features pre-scaled x16 before e4m3 cast; raw dots carry x256, folded out in
// row_reduce (max is monotone). Each tile yields row-max AND col-max.

#define N_ROWS 16384
#define DIM 1024
#define BT 256
#define BKB 128                   // K bytes per tile (two K=64 MFMA steps)
#define NKT (DIM / BKB)           // 8
#define NT (N_ROWS / BT)          // 64
#define NBLK (NT * (NT + 1) / 2)  // 2080 (divisible by 8 -> XCD swizzle)

typedef int   i32x4 __attribute__((ext_vector_type(4)));
typedef int   i32x8 __attribute__((ext_vector_type(8)));
typedef float f32x16 __attribute__((ext_vector_type(16)));

__device__ __forceinline__ void async16(const void* g, void* l) {
  __builtin_amdgcn_global_load_lds(
      (__attribute__((address_space(1))) const void*)g,
      (__attribute__((address_space(3))) void*)l, 16, 0, 0);
}

#define SB0 __builtin_amdgcn_sched_barrier(0)
#define S_BAR()                   \
  do {                            \
    SB0;                          \
    __builtin_amdgcn_s_barrier(); \
    SB0;                          \
  } while (0)
#define WAIT_VM(N) asm volatile("s_waitcnt vmcnt(" #N ")" ::: "memory")
#define WAIT_LGKM0()                                   \
  do {                                                 \
    asm volatile("s_waitcnt lgkmcnt(0)" ::: "memory"); \
    SB0;                                               \
  } while (0)

// ---------------------------------------------------------------- normalize
__global__ __launch_bounds__(256) void normalize_kernel(
    const float* __restrict__ in, unsigned int* __restrict__ outp) {
  const int row = blockIdx.x;
  const int t = threadIdx.x;  // 256 threads x 4 floats
  const float4 v = ((const float4*)(in + (size_t)row * DIM))[t];
  float ss = v.x * v.x + v.y * v.y + v.z * v.z + v.w * v.w;
#pragma unroll
  for (int s = 1; s < 64; s <<= 1) ss += __shfl_xor(ss, s, 64);
  __shared__ float wsum[4];
  const int wave = t >> 6, lane = t & 63;
  if (lane == 0) wsum[wave] = ss;
  __syncthreads();
  const float tot = wsum[0] + wsum[1] + wsum[2] + wsum[3];
  const float scale = 16.f / fmaxf(sqrtf(tot), 1e-12f);
  unsigned int p = __builtin_amdgcn_cvt_pk_fp8_f32(v.x * scale, v.y * scale, 0, false);
  p = __builtin_amdgcn_cvt_pk_fp8_f32(v.z * scale, v.w * scale, p, true);
  outp[(size_t)row * (DIM / 4) + t] = p;
}

// lane reads granules g0=2t, 2t+1 of its row-slot (t = ks*2 + (lane>>5));
// xx = swizzled byte offset of g0, second granule at xx^16.
#define READF(dst, base, off, xx)                                    \
  do {                                                               \
    i32x4 _lo = *(const i32x4*)((base) + (off) + (xx));              \
    i32x4 _hi = *(const i32x4*)((base) + (off) + ((xx) ^ 16));       \
    dst = __builtin_shufflevector(_lo, _hi, 0, 1, 2, 3, 4, 5, 6, 7); \
  } while (0)

#define MFMA32(A, B, MI, NI)                                          \
  acc[MI][NI] = __builtin_amdgcn_mfma_scale_f32_32x32x64_f8f6f4(      \
      A, B, acc[MI][NI], 0, 0, 0, 0x7F7F7F7F, 0, 0x7F7F7F7F)

// stage both panels' next K-slab: 4 gload_lds per thread (1024 thr x 16 B x 2
// rounds = 32 KiB per panel)
#define STAGE(bi, k0)                                                 \
  do {                                                                \
    _Pragma("unroll") for (int r = 0; r < 2; ++r) {                   \
      async16(FA + (k0) + srcoff[r], &lds[bi][0][dst_u + r * 16384]); \
      async16(FB + (k0) + srcoff[r], &lds[bi][1][dst_u + r * 16384]); \
    }                                                                 \
  } while (0)

// -------------------------------------------------- Gram row/col-max GEMM
__global__ __launch_bounds__(1024, 4) void gemm_rowmax(
    const unsigned char* __restrict__ F, float* __restrict__ partial) {
  // XCD-chunked bijective swizzle (2080 % 8 == 0), then triangular decode
  int bid = blockIdx.x;
  bid = (bid & 7) * (NBLK / 8) + (bid >> 3);
  double disc = (double)(2 * NT + 1) * (2 * NT + 1) - 8.0 * (double)bid;
  int it = (int)(((2 * NT + 1) - sqrt(disc)) * 0.5);
  if (it > NT - 1) it = NT - 1;
  while (it > 0 && it * NT - it * (it - 1) / 2 > bid) --it;
  while ((it + 1) * NT - (it + 1) * it / 2 <= bid) ++it;
  const int jt = it + (bid - (it * NT - it * (it - 1) / 2));

  __shared__ __align__(16) unsigned char lds[2][2][BT * BKB];  // 128 KiB

  const int ibase = it * BT, jbase = jt * BT;
  const int tid = threadIdx.x;
  const int wave = tid >> 6, lane = tid & 63;
  const int wi = wave >> 2, wj = wave & 3;  // 4x4 wave grid, 64x64 each
  const int r31 = lane & 31, q2 = lane >> 5;

  const unsigned char* FA = F + (size_t)ibase * DIM;
  const unsigned char* FB = F + (size_t)jbase * DIM;

  // ---- staging addresses (R13 verbatim): granule flat = r*1024 + tid;
  // slot = flat>>3 (row 0..255); lg = (tid&7)^((tid>>3)&7), const/thread.
  const unsigned int lg16 = (unsigned int)(((tid & 7) ^ ((tid >> 3) & 7)) << 4);
  unsigned int srcoff[2];
  srcoff[0] = (unsigned int)(tid >> 3) * 1024u + lg16;
  srcoff[1] = srcoff[0] + 131072u;  // +128 rows
  const unsigned int dst_u = (unsigned int)(tid & ~63) * 16u;

  // ---- fragment read offsets (loop-invariant)
  // frag(mi, ks): row = wi*64 + mi*32 + r31; granule g0 = ks*4 + q2*2.
  const unsigned int a_base = (unsigned int)(wi * 64 + r31) * BKB;  // + mi*4096
  const unsigned int b_base = (unsigned int)(wj * 64 + r31) * BKB;  // + ni*4096
  const int xk0 = ((q2 * 2) ^ (r31 & 7)) << 4;  // ks=0; ks=1 at xk0^64
  const int xk1 = xk0 ^ 64;

  f32x16 acc[2][2] = {};  // [mi][ni] 32x32 tiles (AGPR-resident, 64 regs)
  i32x8 a0, a1, b0, b1;

  STAGE(0, 0);  // prologue: 4 loads in flight

#pragma unroll 1
  for (int kt = 0; kt < NKT; ++kt) {
    const int cur = kt & 1;
    if (kt < NKT - 1) {
      STAGE(cur ^ 1, (kt + 1) * BKB);  // issue next; 8 in flight
      WAIT_VM(4);                      // previous stage landed (issued 1 iter ago)
    } else {
      WAIT_VM(0);  // epilogue drain
    }
    S_BAR();  // acquire lds[cur]
    const unsigned char* cA = &lds[cur][0][0];
    const unsigned char* cB = &lds[cur][1][0];

    // ---- K-step 0 (k bytes [0,64))
    READF(a0, cA, a_base, xk0);
    READF(a1, cA, a_base + 4096, xk0);
    READF(b0, cB, b_base, xk0);
    READF(b1, cB, b_base + 4096, xk0);
    WAIT_LGKM0();
    __builtin_amdgcn_s_setprio(1);
    MFMA32(a0, b0, 0, 0);
    MFMA32(a1, b0, 1, 0);
    MFMA32(a0, b1, 0, 1);
    MFMA32(a1, b1, 1, 1);
    __builtin_amdgcn_s_setprio(0);
    SB0;
    // ---- K-step 1 (k bytes [64,128))
    READF(a0, cA, a_base, xk1);
    READF(a1, cA, a_base + 4096, xk1);
    READF(b0, cB, b_base, xk1);
    READF(b1, cB, b_base + 4096, xk1);
    WAIT_LGKM0();
    __builtin_amdgcn_s_setprio(1);
    MFMA32(a0, b0, 0, 0);
    MFMA32(a1, b0, 1, 0);
    MFMA32(a0, b1, 0, 1);
    MFMA32(a1, b1, 1, 1);
    __builtin_amdgcn_s_setprio(0);
    S_BAR();  // release lds[cur] (reads drained by lgkm0 above)
  }

  // ---------------- epilogue: row/col max (alias dead staging LDS)
  float(*red)[4] = (float(*)[4]) & lds[0][0][0];           // [256][4] over wj
  float(*redc)[4] = (float(*)[4])(&lds[0][0][0] + 4096);   // [256][4] over wi

  // C/D layout (32x32): col = lane&31, row = (reg&3) + 8*(reg>>2) + 4*q2.
#pragma unroll
  for (int mi = 0; mi < 2; ++mi) {
#pragma unroll
    for (int reg = 0; reg < 16; ++reg) {
      const int rit = (reg & 3) + 8 * (reg >> 2) + 4 * q2;
      const int rl = wi * 64 + mi * 32 + rit;
      const int rowg = ibase + rl;
      float m = -INFINITY;
#pragma unroll
      for (int ni = 0; ni < 2; ++ni) {
        const int colg = jbase + wj * 64 + ni * 32 + r31;
        const float v = acc[mi][ni][reg];
        m = (rowg == colg) ? m : fmaxf(m, v);
      }
#pragma unroll
      for (int s = 1; s < 32; s <<= 1) m = fmaxf(m, __shfl_xor(m, s, 64));
      if (r31 == 0) red[rl][wj] = m;
    }
  }
  if (it != jt) {  // col-max (off-diagonal tiles: no diag elements present)
#pragma unroll
    for (int ni = 0; ni < 2; ++ni) {
      float m = -INFINITY;
#pragma unroll
      for (int mi = 0; mi < 2; ++mi)
#pragma unroll
        for (int reg = 0; reg < 16; ++reg) m = fmaxf(m, acc[mi][ni][reg]);
      m = fmaxf(m, __shfl_xor(m, 32, 64));  // combine row-halves
      if (q2 == 0) redc[wj * 64 + ni * 32 + r31][wi] = m;
    }
  }
  __syncthreads();
  if (tid < BT) {
    const float a = fmaxf(red[tid][0], red[tid][1]);
    const float b = fmaxf(red[tid][2], red[tid][3]);
    partial[(size_t)jt * N_ROWS + ibase + tid] = fmaxf(a, b);
  } else if (tid < 2 * BT && it != jt) {
    const int c = tid - BT;
    const float a = fmaxf(redc[c][0], redc[c][1]);
    const float b = fmaxf(redc[c][2], redc[c][3]);
    partial[(size_t)it * N_ROWS + jbase + c] = fmaxf(a, b);
  }
}

// ------------------------------------------------------------- reductions
__global__ __launch_bounds__(256) void row_reduce(
    const float* __restrict__ partial, float* __restrict__ blocksum) {
  const int r = blockIdx.x * 256 + threadIdx.x;
  float m = -INFINITY;
  for (int p = 0; p < NT; ++p)
    m = fmaxf(m, partial[(size_t)p * N_ROWS + r]);
  // raw dot carries x256 (features scaled x16): 2 - 2*(m/256) = 2 - m/128
  const float d2 = fmaxf(2.f - m * (1.f / 128.f), 0.f);
  float term = logf(sqrtf(d2) + 1e-8f);
#pragma unroll
  for (int s = 1; s < 64; s <<= 1) term += __shfl_xor(term, s, 64);
  __shared__ float wsum[4];
  const int wave = threadIdx.x >> 6, lane = threadIdx.x & 63;
  if (lane == 0) wsum[wave] = term;
  __syncthreads();
  if (threadIdx.x == 0)
    blocksum[blockIdx.x] = wsum[0] + wsum[1] + wsum[2] + wsum[3];
}

__global__ void finalize(const float* __restrict__ blocksum,
                         float* __restrict__ out) {
  float v = blocksum[threadIdx.x];
#pragma unroll
  for (int s = 1; s < 64; s <<= 1) v += __shfl_xor(v, s, 64);
  if (threadIdx.x == 0) out[0] = -v / (float)N_ROWS;
}

// ---------------------------------------------------------------- launcher
extern "C" void kernel_launch(void* const* d_in, const int* in_sizes, int n_in,
                              void* d_out, int out_size, void* d_ws, size_t ws_size,
                              hipStream_t stream) {
  const float* feats = (const float*)d_in[0];
  float* out = (float*)d_out;
  char* ws = (char*)d_ws;

  // ws: [0,16MB) fp8 features; [16MB,20MB) partial [64][16384] f32; then sums.
  unsigned char* f8 = (unsigned char*)ws;
  float* partial = (float*)(ws + (size_t)N_ROWS * DIM);
  float* blocksum =
      (float*)(ws + (size_t)N_ROWS * DIM + (size_t)NT * N_ROWS * 4);

  normalize_kernel<<<N_ROWS, 256, 0, stream>>>(feats, (unsigned int*)f8);
  gemm_rowmax<<<NBLK, 1024, 0, stream>>>(f8, partial);
  row_reduce<<<N_ROWS / 256, 256, 0, stream>>>(partial, blocksum);
  finalize<<<1, 64, 0, stream>>>(blocksum, out);
}

// Round 9
// 308.976 us; speedup vs baseline: 5.2837x; 1.0118x over previous
//
#include <hip/hip_runtime.h>
#include <math.h>

// KoLeo loss: dist_i = sqrt(2 - 2*max_{j!=i} <fhat_i, fhat_j>); loss = -mean(log(dist+1e-8))
// R18: m201-anatomy port (the only structure measured >35% of MFMA ceiling):
// 256^2 tile, 8 waves (2x4, 128x64 each, 2/SIMD -> 256-reg budget), per K-tile
// FOUR phases = C-quadrants (64x32, 8 MFMA), each phase:
//   {ds_read batch ; stage 1 half-tile ; barrier ; lgkm(0) ; setprio ;
//    8 MFMA ; setprio ; barrier}
// A-frags cached across the nh-pair (24 b128 reads/wave/tile, was 32); B read
// once at phase 0. vmcnt(0) ONLY at phase 0 (drains the 4 half-tiles issued a
// full K-tile earlier -> instant); staging granularity 1 half-tile (2 loads)
// per phase. Evidence: R9-R17 pin every 1-2-phase structure at dur x util ==
// 60 us MFMA floor (25-32%); m196/m218/m218b isolate the per-phase fine
// interleave + counted waits + setprio-with-role-split as the levers (62% on
// the bf16 twin of this geometry). Regs: acc 128 + afr 32 + bfr 32 + addr
// ~20 = ~215 < 256. Staging/swizzle/epilogue verbatim from verified R13/R15.
// Features pre-scaled x16 before e4m3 cast; raw dots carry x256, folded out in
// row_reduce (max is monotone). Each tile yields row-max AND col-max.

#define N_ROWS 16384
#define DIM 1024
#define BT 256
#define BKB 128                   // K bytes per tile (one K=128 MFMA)
#define NKT (DIM / BKB)           // 8
#define NT (N_ROWS / BT)          // 64
#define NBLK (NT * (NT + 1) / 2)  // 2080 (divisible by 8 -> XCD swizzle)

typedef int   i32x4 __attribute__((ext_vector_type(4)));
typedef int   i32x8 __attribute__((ext_vector_type(8)));
typedef float f32x4 __attribute__((ext_vector_type(4)));

__device__ __forceinline__ void async16(const void* g, void* l) {
  __builtin_amdgcn_global_load_lds(
      (__attribute__((address_space(1))) const void*)g,
      (__attribute__((address_space(3))) void*)l, 16, 0, 0);
}

#define SB0 __builtin_amdgcn_sched_barrier(0)
#define S_BAR()                   \
  do {                            \
    SB0;                          \
    __builtin_amdgcn_s_barrier(); \
    SB0;                          \
  } while (0)
#define WAIT_VM(N) asm volatile("s_waitcnt vmcnt(" #N ")" ::: "memory")
#define WAIT_LGKM0()                                   \
  do {                                                 \
    asm volatile("s_waitcnt lgkmcnt(0)" ::: "memory"); \
    SB0;                                               \
  } while (0)

// ---------------------------------------------------------------- normalize
__global__ __launch_bounds__(256) void normalize_kernel(
    const float* __restrict__ in, unsigned int* __restrict__ outp) {
  const int row = blockIdx.x;
  const int t = threadIdx.x;  // 256 threads x 4 floats
  const float4 v = ((const float4*)(in + (size_t)row * DIM))[t];
  float ss = v.x * v.x + v.y * v.y + v.z * v.z + v.w * v.w;
#pragma unroll
  for (int s = 1; s < 64; s <<= 1) ss += __shfl_xor(ss, s, 64);
  __shared__ float wsum[4];
  const int wave = t >> 6, lane = t & 63;
  if (lane == 0) wsum[wave] = ss;
  __syncthreads();
  const float tot = wsum[0] + wsum[1] + wsum[2] + wsum[3];
  const float scale = 16.f / fmaxf(sqrtf(tot), 1e-12f);
  unsigned int p = __builtin_amdgcn_cvt_pk_fp8_f32(v.x * scale, v.y * scale, 0, false);
  p = __builtin_amdgcn_cvt_pk_fp8_f32(v.z * scale, v.w * scale, p, true);
  outp[(size_t)row * (DIM / 4) + t] = p;
}

// lane reads logical granules 2q,2q+1 of its row slot; x0 = swizzled byte
// offset, second granule at x0^16 (since (2q+1)^k == (2q^k)^1).
#define READ_FRAG(dst, base, off)                                    \
  do {                                                               \
    i32x4 _lo = *(const i32x4*)((base) + (off) + x0);                \
    i32x4 _hi = *(const i32x4*)((base) + (off) + (x0 ^ 16));         \
    dst = __builtin_shufflevector(_lo, _hi, 0, 1, 2, 3, 4, 5, 6, 7); \
  } while (0)

// MFMA quadrant (A-frags afr[0..3] x B-frags bfr[B0],bfr[B0+1]) into
// acc[AC+0..3][B0..B0+1]
#define MFMA_QUAD(AC, B0)                                                \
  do {                                                                   \
    __builtin_amdgcn_s_setprio(1);                                       \
    _Pragma("unroll") for (int a = 0; a < 4; ++a) {                      \
      _Pragma("unroll") for (int b = 0; b < 2; ++b) {                    \
        acc[(AC) + a][(B0) + b] =                                        \
            __builtin_amdgcn_mfma_scale_f32_16x16x128_f8f6f4(            \
                afr[a], bfr[(B0) + b], acc[(AC) + a][(B0) + b], 0, 0,    \
                0, 0x7F7F7F7F, 0, 0x7F7F7F7F); /* unit e8m0 scales */    \
      }                                                                  \
    }                                                                    \
    __builtin_amdgcn_s_setprio(0);                                       \
  } while (0)

// stage one half-tile (128 rows x 128 B = 16 KB): 2 gload_lds per thread
#define STAGE_HALF(bi, panel, half, k0)                                      \
  do {                                                                       \
    const unsigned char* _s = (panel) ? FB : FA;                             \
    _Pragma("unroll") for (int r = 0; r < 2; ++r)                            \
        async16(_s + (k0) + (half)*131072u + sh_src + r * 65536u,            \
                &lds[bi][panel][(half)*16384u + sh_dst + r * 8192u]);        \
  } while (0)

// -------------------------------------------------- Gram row/col-max GEMM
__global__ __launch_bounds__(512, 2) void gemm_rowmax(
    const unsigned char* __restrict__ F, float* __restrict__ partial) {
  // XCD-chunked bijective swizzle (2080 % 8 == 0), then triangular decode
  int bid = blockIdx.x;
  bid = (bid & 7) * (NBLK / 8) + (bid >> 3);
  double disc = (double)(2 * NT + 1) * (2 * NT + 1) - 8.0 * (double)bid;
  int it = (int)(((2 * NT + 1) - sqrt(disc)) * 0.5);
  if (it > NT - 1) it = NT - 1;
  while (it > 0 && it * NT - it * (it - 1) / 2 > bid) --it;
  while ((it + 1) * NT - (it + 1) * it / 2 <= bid) ++it;
  const int jt = it + (bid - (it * NT - it * (it - 1) / 2));

  __shared__ __align__(16) unsigned char lds[2][2][BT * BKB];  // 128 KiB

  const int ibase = it * BT, jbase = jt * BT;
  const int tid = threadIdx.x;
  const int wave = tid >> 6, lane = tid & 63;
  const int wi = wave >> 2, wj = wave & 3;  // 2x4 wave grid, 128x64 each
  const int quad = lane >> 4, r16 = lane & 15;

  const unsigned char* FA = F + (size_t)ibase * DIM;
  const unsigned char* FB = F + (size_t)jbase * DIM;

  // ---- staging addresses: within a 128-row slab, granule flat = r*512+tid;
  // slot = r*64 + (tid>>3); lg = (tid&7)^((tid>>3)&7) (const: 64%8==0).
  const unsigned int lg16 = (unsigned int)(((tid & 7) ^ ((tid >> 3) & 7)) << 4);
  const unsigned int sh_src = (unsigned int)(tid >> 3) * 1024u + lg16;
  const unsigned int sh_dst = (unsigned int)(tid & ~63) * 16u;

  // ---- fragment read offsets (loop-invariant)
  const int x0 = ((2 * quad) ^ (r16 & 7)) << 4;
  const unsigned int a_rd = (unsigned int)(wi * 128 + r16) * BKB;  // +mh*8192+a*2048
  const unsigned int b_rd = (unsigned int)(wj * 64 + r16) * BKB;   // +nb*2048

  f32x4 acc[8][4] = {};   // [mi][ni] 16x16 tiles (AGPR-resident, 128 regs)
  i32x8 afr[4], bfr[4];   // A cached per mh; B cached for the whole tile

  // prologue: stage all 4 half-tiles of kt=0 into buf 0 (8 loads in flight)
  STAGE_HALF(0, 0, 0, 0);
  STAGE_HALF(0, 0, 1, 0);
  STAGE_HALF(0, 1, 0, 0);
  STAGE_HALF(0, 1, 1, 0);

#pragma unroll 1
  for (int kt = 0; kt < NKT; ++kt) {
    const int cur = kt & 1, nxt = cur ^ 1;
    const int k0n = (kt + 1) * BKB;
    const unsigned char* cA = &lds[cur][0][0];
    const unsigned char* cB = &lds[cur][1][0];
    const bool st = (kt < NKT - 1);

    // ---- phase 0: A(mh0) + B(all) reads; stage A-lo(next); quad (mh0,nh0)
    WAIT_VM(0);  // cur's 4 half-tiles (issued a full K-tile ago) -> instant
    S_BAR();     // all waves drained => all LDS writes of cur visible
    READ_FRAG(afr[0], cA, a_rd);
    READ_FRAG(afr[1], cA, a_rd + 2048);
    READ_FRAG(afr[2], cA, a_rd + 4096);
    READ_FRAG(afr[3], cA, a_rd + 6144);
    READ_FRAG(bfr[0], cB, b_rd);
    READ_FRAG(bfr[1], cB, b_rd + 2048);
    READ_FRAG(bfr[2], cB, b_rd + 4096);
    READ_FRAG(bfr[3], cB, b_rd + 6144);
    if (st) STAGE_HALF(nxt, 0, 0, k0n);
    S_BAR();
    WAIT_LGKM0();
    MFMA_QUAD(0, 0);
    S_BAR();
    // ---- phase 1: no reads; stage A-hi(next); quad (mh0,nh1)
    if (st) STAGE_HALF(nxt, 0, 1, k0n);
    S_BAR();
    MFMA_QUAD(0, 2);
    S_BAR();
    // ---- phase 2: A(mh1) reads; stage B-lo(next); quad (mh1,nh0)
    READ_FRAG(afr[0], cA, a_rd + 8192);
    READ_FRAG(afr[1], cA, a_rd + 10240);
    READ_FRAG(afr[2], cA, a_rd + 12288);
    READ_FRAG(afr[3], cA, a_rd + 14336);
    if (st) STAGE_HALF(nxt, 1, 0, k0n);
    S_BAR();
    WAIT_LGKM0();
    MFMA_QUAD(4, 0);
    S_BAR();
    // ---- phase 3: no reads; stage B-hi(next); quad (mh1,nh1)
    if (st) STAGE_HALF(nxt, 1, 1, k0n);
    S_BAR();
    MFMA_QUAD(4, 2);
    S_BAR();
  }

  // ---------------- epilogue: row/col max (alias dead staging LDS)
  __syncthreads();
  float(*red)[4] = (float(*)[4]) & lds[0][0][0];          // [256][4] over wj
  float(*redc)[2] = (float(*)[2])(&lds[0][0][0] + 4096);  // [256][2] over wi

  // C/D layout (16x16): col = lane&15, row = quad*4 + reg.
#pragma unroll
  for (int mi = 0; mi < 8; ++mi) {
#pragma unroll
    for (int r = 0; r < 4; ++r) {
      const int rl = wi * 128 + mi * 16 + quad * 4 + r;
      const int rowg = ibase + rl;
      float m = -INFINITY;
#pragma unroll
      for (int ni = 0; ni < 4; ++ni) {
        const int colg = jbase + wj * 64 + ni * 16 + r16;
        const float v = acc[mi][ni][r];
        m = (rowg == colg) ? m : fmaxf(m, v);
      }
#pragma unroll
      for (int s = 1; s < 16; s <<= 1) m = fmaxf(m, __shfl_xor(m, s, 64));
      if (r16 == 0) red[rl][wj] = m;
    }
  }
  if (it != jt) {  // col-max (off-diagonal tiles: no diag elements present)
#pragma unroll
    for (int ni = 0; ni < 4; ++ni) {
      float m = -INFINITY;
#pragma unroll
      for (int mi = 0; mi < 8; ++mi)
#pragma unroll
        for (int r = 0; r < 4; ++r) m = fmaxf(m, acc[mi][ni][r]);
      m = fmaxf(m, __shfl_xor(m, 16, 64));  // reduce across quads
      m = fmaxf(m, __shfl_xor(m, 32, 64));
      if (quad == 0) redc[wj * 64 + ni * 16 + r16][wi] = m;
    }
  }
  __syncthreads();
  if (tid < BT) {
    const float a = fmaxf(red[tid][0], red[tid][1]);
    const float b = fmaxf(red[tid][2], red[tid][3]);
    partial[(size_t)jt * N_ROWS + ibase + tid] = fmaxf(a, b);
  } else if (it != jt) {
    const int c = tid - BT;
    partial[(size_t)it * N_ROWS + jbase + c] = fmaxf(redc[c][0], redc[c][1]);
  }
}

// ------------------------------------------------------------- reductions
__global__ __launch_bounds__(256) void row_reduce(
    const float* __restrict__ partial, float* __restrict__ blocksum) {
  const int r = blockIdx.x * 256 + threadIdx.x;
  float m = -INFINITY;
  for (int p = 0; p < NT; ++p)
    m = fmaxf(m, partial[(size_t)p * N_ROWS + r]);
  // raw dot carries x256 (features scaled x16): 2 - 2*(m/256) = 2 - m/128
  const float d2 = fmaxf(2.f - m * (1.f / 128.f), 0.f);
  float term = logf(sqrtf(d2) + 1e-8f);
#pragma unroll
  for (int s = 1; s < 64; s <<= 1) term += __shfl_xor(term, s, 64);
  __shared__ float wsum[4];
  const int wave = threadIdx.x >> 6, lane = threadIdx.x & 63;
  if (lane == 0) wsum[wave] = term;
  __syncthreads();
  if (threadIdx.x == 0)
    blocksum[blockIdx.x] = wsum[0] + wsum[1] + wsum[2] + wsum[3];
}

__global__ void finalize(const float* __restrict__ blocksum,
                         float* __restrict__ out) {
  float v = blocksum[threadIdx.x];
#pragma unroll
  for (int s = 1; s < 64; s <<= 1) v += __shfl_xor(v, s, 64);
  if (threadIdx.x == 0) out[0] = -v / (float)N_ROWS;
}

// ---------------------------------------------------------------- launcher
extern "C" void kernel_launch(void* const* d_in, const int* in_sizes, int n_in,
                              void* d_out, int out_size, void* d_ws, size_t ws_size,
                              hipStream_t stream) {
  const float* feats = (const float*)d_in[0];
  float* out = (float*)d_out;
  char* ws = (char*)d_ws;

  // ws: [0,16MB) fp8 features; [16MB,20MB) partial [64][16384] f32; then sums.
  unsigned char* f8 = (unsigned char*)ws;
  float* partial = (float*)(ws + (size_t)N_ROWS * DIM);
  float* blocksum =
      (float*)(ws + (size_t)N_ROWS * DIM + (size_t)NT * N_ROWS * 4);

  normalize_kernel<<<N_ROWS, 256, 0, stream>>>(feats, (unsigned int*)f8);
  gemm_rowmax<<<NBLK, 512, 0, stream>>>(f8, partial);
  row_reduce<<<N_ROWS / 256, 256, 0, stream>>>(partial, blocksum);
  finalize<<<1, 64, 0, stream>>>(blocksum, out);
}

// Round 10
// 279.795 us; speedup vs baseline: 5.8348x; 1.1043x over previous
//
#include <hip/hip_runtime.h>
#include <math.h>

// KoLeo loss: dist_i = sqrt(2 - 2*max_{j!=i} <fhat_i, fhat_j>); loss = -mean(log(dist+1e-8))
// FINAL (R19) = R13 verbatim, the session-best verified kernel (281.2 us).
// 256^2 block tile, 16 waves of 64x64 (64 VGPR + 64 AGPR -> 4 waves/SIMD),
// 1024 threads, 128 KiB LDS double-buffer, minimal counted 2-phase schedule:
//   STAGE(next) ; vmcnt(4) [prev stage landed] ; barrier ; frag reads ;
//   16 MFMA ; lgkm(0) ; barrier.  Never vmcnt(0) in the main loop.
// Session evidence (R9-R18): nine structures (2-phase 128^2/256^2, counted
// 8-phase, register-direct, in-tile lgkm pipeline, 1-barrier pinned order,
// 32x32 shape, quadrant phases) ALL obey dur x MfmaUtil == 60 us MX-MFMA
// floor at 25-32% efficiency; learn-loop's own MX references cap at 32-38%
// in mixed streams (m148/m153/m160). bf16 best-case (62% of 2.5PF) == 180 us
// == no headroom over this kernel's 195 us gemm. Conclusion: mixed-stream
// scaled-MFMA efficiency ~1/3 of ubench is the structural limit for HIP
// source on gfx950; this kernel sits at it.
// 16B-granule XOR swizzle (granule g of row r at phys g^(r&7)), linear
// gload_lds dest + pre-swizzled source (rule #21). red/redc alias dead LDS.
// Features pre-scaled x16 before e4m3 cast; raw dots carry x256, folded out in
// row_reduce (max is monotone). Each tile yields row-max AND col-max.

#define N_ROWS 16384
#define DIM 1024
#define BT 256
#define BKB 128                   // K bytes per tile (one K=128 MFMA)
#define NKT (DIM / BKB)           // 8
#define NT (N_ROWS / BT)          // 64
#define NBLK (NT * (NT + 1) / 2)  // 2080 (divisible by 8 -> XCD swizzle)

typedef int   i32x4 __attribute__((ext_vector_type(4)));
typedef int   i32x8 __attribute__((ext_vector_type(8)));
typedef float f32x4 __attribute__((ext_vector_type(4)));

__device__ __forceinline__ void async16(const void* g, void* l) {
  __builtin_amdgcn_global_load_lds(
      (__attribute__((address_space(1))) const void*)g,
      (__attribute__((address_space(3))) void*)l, 16, 0, 0);
}

// Raw barrier with compile-time motion fences (rule #18).
#define S_BAR()                        \
  do {                                 \
    __builtin_amdgcn_sched_barrier(0); \
    __builtin_amdgcn_s_barrier();      \
    __builtin_amdgcn_sched_barrier(0); \
  } while (0)
#define WAIT_VM(N) asm volatile("s_waitcnt vmcnt(" #N ")" ::: "memory")
#define WAIT_LGKM()                                    \
  do {                                                 \
    asm volatile("s_waitcnt lgkmcnt(0)" ::: "memory"); \
    __builtin_amdgcn_sched_barrier(0);                 \
  } while (0)

// ---------------------------------------------------------------- normalize
__global__ __launch_bounds__(256) void normalize_kernel(
    const float* __restrict__ in, unsigned int* __restrict__ outp) {
  const int row = blockIdx.x;
  const int t = threadIdx.x;  // 256 threads x 4 floats
  const float4 v = ((const float4*)(in + (size_t)row * DIM))[t];
  float ss = v.x * v.x + v.y * v.y + v.z * v.z + v.w * v.w;
#pragma unroll
  for (int s = 1; s < 64; s <<= 1) ss += __shfl_xor(ss, s, 64);
  __shared__ float wsum[4];
  const int wave = t >> 6, lane = t & 63;
  if (lane == 0) wsum[wave] = ss;
  __syncthreads();
  const float tot = wsum[0] + wsum[1] + wsum[2] + wsum[3];
  const float scale = 16.f / fmaxf(sqrtf(tot), 1e-12f);
  unsigned int p = __builtin_amdgcn_cvt_pk_fp8_f32(v.x * scale, v.y * scale, 0, false);
  p = __builtin_amdgcn_cvt_pk_fp8_f32(v.z * scale, v.w * scale, p, true);
  outp[(size_t)row * (DIM / 4) + t] = p;
}

// lane reads logical granules 2q,2q+1 of its slot; x0 = swizzled byte offset,
// second granule at x0^16 (since (2q+1)^k == (2q^k)^1).
#define READ_FRAG(dst, base, off)                                    \
  do {                                                               \
    i32x4 _lo = *(const i32x4*)((base) + (off) + x0);                \
    i32x4 _hi = *(const i32x4*)((base) + (off) + (x0 ^ 16));         \
    dst = __builtin_shufflevector(_lo, _hi, 0, 1, 2, 3, 4, 5, 6, 7); \
  } while (0)

// stage both panels' next K-slab: 4 gload_lds per wave (2 A + 2 B)
#define STAGE(bi, k0)                                                 \
  do {                                                                \
    _Pragma("unroll") for (int r = 0; r < 2; ++r) {                   \
      async16(FA + (k0) + srcoff[r], &lds[bi][0][dst_u + r * 16384]); \
      async16(FB + (k0) + srcoff[r], &lds[bi][1][dst_u + r * 16384]); \
    }                                                                 \
  } while (0)

// -------------------------------------------------- Gram row/col-max GEMM
__global__ __launch_bounds__(1024, 4) void gemm_rowmax(
    const unsigned char* __restrict__ F, float* __restrict__ partial) {
  // XCD-chunked bijective swizzle (2080 % 8 == 0), then triangular decode
  int bid = blockIdx.x;
  bid = (bid & 7) * (NBLK / 8) + (bid >> 3);
  double disc = (double)(2 * NT + 1) * (2 * NT + 1) - 8.0 * (double)bid;
  int it = (int)(((2 * NT + 1) - sqrt(disc)) * 0.5);
  if (it > NT - 1) it = NT - 1;
  while (it > 0 && it * NT - it * (it - 1) / 2 > bid) --it;
  while ((it + 1) * NT - (it + 1) * it / 2 <= bid) ++it;
  const int jt = it + (bid - (it * NT - it * (it - 1) / 2));

  __shared__ __align__(16) unsigned char lds[2][2][BT * BKB];  // 128 KiB

  const int ibase = it * BT, jbase = jt * BT;
  const int tid = threadIdx.x;
  const int wave = tid >> 6, lane = tid & 63;
  const int wi = wave >> 2, wj = wave & 3;  // 4x4 wave grid, 64x64 each
  const int quad = lane >> 4, r16 = lane & 15;

  const unsigned char* FA = F + (size_t)ibase * DIM;
  const unsigned char* FB = F + (size_t)jbase * DIM;

  // ---- staging addresses: granule flat = r*1024 + tid; slot = flat>>3
  // (row 0..255); logical granule lg = (flat&7)^(slot&7) -- constant per
  // thread since 1024 % 8 == 0. Per-thread src offset affine in r.
  const unsigned int lg16 = (unsigned int)(((tid & 7) ^ ((tid >> 3) & 7)) << 4);
  unsigned int srcoff[2];
  srcoff[0] = (unsigned int)(tid >> 3) * 1024u + lg16;
  srcoff[1] = srcoff[0] + 131072u;  // +128 rows
  const unsigned int dst_u = (unsigned int)(tid & ~63) * 16u;

  // ---- fragment read offsets (loop-invariant)
  const int x0 = ((2 * quad) ^ (r16 & 7)) << 4;
  const unsigned int a_rd = (unsigned int)(wi * 64 + r16) * BKB;  // + mi*2048
  const unsigned int b_rd = (unsigned int)(wj * 64 + r16) * BKB;  // + ni*2048

  f32x4 acc[4][4] = {};  // [mi][ni] 16x16 tiles (AGPR-resident)
  i32x8 afr[4], bfr;

  STAGE(0, 0);  // prologue: 4 loads in flight

#pragma unroll 1
  for (int kt = 0; kt < NKT; ++kt) {
    const int cur = kt & 1;
    if (kt < NKT - 1) {
      STAGE(cur ^ 1, (kt + 1) * BKB);  // issue next; 8 in flight
      WAIT_VM(4);                      // previous stage landed (issued ~1 iter ago)
    } else {
      WAIT_VM(0);  // epilogue drain
    }
    S_BAR();
    const unsigned char* cA = &lds[cur][0][0];
    const unsigned char* cB = &lds[cur][1][0];
#pragma unroll
    for (int mi = 0; mi < 4; ++mi) READ_FRAG(afr[mi], cA, a_rd + mi * 2048);
#pragma unroll
    for (int ni = 0; ni < 4; ++ni) {
      READ_FRAG(bfr, cB, b_rd + ni * 2048);
#pragma unroll
      for (int mi = 0; mi < 4; ++mi)
        acc[mi][ni] = __builtin_amdgcn_mfma_scale_f32_16x16x128_f8f6f4(
            afr[mi], bfr, acc[mi][ni], 0, 0,  // cbsz=0 (fp8), blgp=0 (fp8)
            0, 0x7F7F7F7F, 0, 0x7F7F7F7F);    // unit e8m0 scales
    }
    WAIT_LGKM();  // reads of lds[cur] complete before releasing the buffer
    S_BAR();
  }

  // ---------------- epilogue: row/col max (alias dead staging LDS --
  // lds[0] last read at kt=6, guarded by that iteration's end barrier)
  float(*red)[4] = (float(*)[4]) & lds[0][0][0];           // [256][4] over wj
  float(*redc)[4] = (float(*)[4])(&lds[0][0][0] + 4096);   // [256][4] over wi

  // C/D layout (16x16): col = lane&15, row = quad*4 + reg.
#pragma unroll
  for (int mi = 0; mi < 4; ++mi) {
#pragma unroll
    for (int r = 0; r < 4; ++r) {
      const int rl = wi * 64 + mi * 16 + quad * 4 + r;
      const int rowg = ibase + rl;
      float m = -INFINITY;
#pragma unroll
      for (int ni = 0; ni < 4; ++ni) {
        const int colg = jbase + wj * 64 + ni * 16 + r16;
        const float v = acc[mi][ni][r];
        m = (rowg == colg) ? m : fmaxf(m, v);
      }
#pragma unroll
      for (int s = 1; s < 16; s <<= 1) m = fmaxf(m, __shfl_xor(m, s, 64));
      if (r16 == 0) red[rl][wj] = m;
    }
  }
  if (it != jt) {  // col-max (off-diagonal tiles: no diag elements present)
#pragma unroll
    for (int ni = 0; ni < 4; ++ni) {
      float m = -INFINITY;
#pragma unroll
      for (int mi = 0; mi < 4; ++mi)
#pragma unroll
        for (int r = 0; r < 4; ++r) m = fmaxf(m, acc[mi][ni][r]);
      m = fmaxf(m, __shfl_xor(m, 16, 64));  // reduce across quads
      m = fmaxf(m, __shfl_xor(m, 32, 64));
      if (quad == 0) redc[wj * 64 + ni * 16 + r16][wi] = m;
    }
  }
  __syncthreads();
  if (tid < BT) {
    const float a = fmaxf(red[tid][0], red[tid][1]);
    const float b = fmaxf(red[tid][2], red[tid][3]);
    partial[(size_t)jt * N_ROWS + ibase + tid] = fmaxf(a, b);
  } else if (tid < 2 * BT && it != jt) {
    const int c = tid - BT;
    const float a = fmaxf(redc[c][0], redc[c][1]);
    const float b = fmaxf(redc[c][2], redc[c][3]);
    partial[(size_t)it * N_ROWS + jbase + c] = fmaxf(a, b);
  }
}

// ------------------------------------------------------------- reductions
__global__ __launch_bounds__(256) void row_reduce(
    const float* __restrict__ partial, float* __restrict__ blocksum) {
  const int r = blockIdx.x * 256 + threadIdx.x;
  float m = -INFINITY;
  for (int p = 0; p < NT; ++p)
    m = fmaxf(m, partial[(size_t)p * N_ROWS + r]);
  // raw dot carries x256 (features scaled x16): 2 - 2*(m/256) = 2 - m/128
  const float d2 = fmaxf(2.f - m * (1.f / 128.f), 0.f);
  float term = logf(sqrtf(d2) + 1e-8f);
#pragma unroll
  for (int s = 1; s < 64; s <<= 1) term += __shfl_xor(term, s, 64);
  __shared__ float wsum[4];
  const int wave = threadIdx.x >> 6, lane = threadIdx.x & 63;
  if (lane == 0) wsum[wave] = term;
  __syncthreads();
  if (threadIdx.x == 0)
    blocksum[blockIdx.x] = wsum[0] + wsum[1] + wsum[2] + wsum[3];
}

__global__ void finalize(const float* __restrict__ blocksum,
                         float* __restrict__ out) {
  float v = blocksum[threadIdx.x];
#pragma unroll
  for (int s = 1; s < 64; s <<= 1) v += __shfl_xor(v, s, 64);
  if (threadIdx.x == 0) out[0] = -v / (float)N_ROWS;
}

// ---------------------------------------------------------------- launcher
extern "C" void kernel_launch(void* const* d_in, const int* in_sizes, int n_in,
                              void* d_out, int out_size, void* d_ws, size_t ws_size,
                              hipStream_t stream) {
  const float* feats = (const float*)d_in[0];
  float* out = (float*)d_out;
  char* ws = (char*)d_ws;

  // ws: [0,16MB) fp8 features; [16MB,20MB) partial [64][16384] f32; then sums.
  unsigned char* f8 = (unsigned char*)ws;
  float* partial = (float*)(ws + (size_t)N_ROWS * DIM);
  float* blocksum =
      (float*)(ws + (size_t)N_ROWS * DIM + (size_t)NT * N_ROWS * 4);

  normalize_kernel<<<N_ROWS, 256, 0, stream>>>(feats, (unsigned int*)f8);
  gemm_rowmax<<<NBLK, 1024, 0, stream>>>(f8, partial);
  row_reduce<<<N_ROWS / 256, 256, 0, stream>>>(partial, blocksum);
  finalize<<<1, 64, 0, stream>>>(blocksum, out);
}